// Round 2
// baseline (2427.308 us; speedup 1.0000x reference)
//
#include <hip/hip_runtime.h>
#include <hip/hip_bf16.h>

#define B 16
#define C 512
#define W 4096
#define HEADS 8
#define HD 64
#define GROUPS 32
#define HIDDEN 512
#define OUT3 1536
#define CPG 16
#define GSIZE (CPG * W)
#define EPS 1e-5f

using bf16 = __hip_bfloat16;

__device__ __forceinline__ float bf_lo(unsigned u) { return __uint_as_float(u << 16); }
__device__ __forceinline__ float bf_hi(unsigned u) { return __uint_as_float(u & 0xffff0000u); }
__device__ __forceinline__ unsigned short f2bf(float f) {
    unsigned u = __float_as_uint(f);
    unsigned r = 0x7fffu + ((u >> 16) & 1u);
    return (unsigned short)((u + r) >> 16);
}
__device__ __forceinline__ unsigned pack2(float a, float b) {
    return (unsigned)f2bf(a) | ((unsigned)f2bf(b) << 16);
}

#define FMA16(a, bb)                                                                      \
    acc[0][0] += a.x * bb.x; acc[0][1] += a.x * bb.y; acc[0][2] += a.x * bb.z; acc[0][3] += a.x * bb.w; \
    acc[1][0] += a.y * bb.x; acc[1][1] += a.y * bb.y; acc[1][2] += a.y * bb.z; acc[1][3] += a.y * bb.w; \
    acc[2][0] += a.z * bb.x; acc[2][1] += a.z * bb.y; acc[2][2] += a.z * bb.z; acc[2][3] += a.z * bb.w; \
    acc[3][0] += a.w * bb.x; acc[3][1] += a.w * bb.y; acc[3][2] += a.w * bb.z; acc[3][3] += a.w * bb.w;

// ---------------- K1: GroupNorm stats (mean, rstd) per (b, group) ----------------
// Each group is a contiguous 65536-float chunk of x. 512 blocks.
__global__ __launch_bounds__(256) void gn_stats_kernel(const float* __restrict__ x,
                                                       float2* __restrict__ stats) {
    __shared__ float s1[256], s2[256];
    int bg = blockIdx.x;
    const float4* p4 = (const float4*)(x + (size_t)bg * GSIZE);
    float sum = 0.f, sq = 0.f;
    for (int i = threadIdx.x; i < GSIZE / 4; i += 256) {
        float4 u = p4[i];
        sum += u.x + u.y + u.z + u.w;
        sq += u.x * u.x + u.y * u.y + u.z * u.z + u.w * u.w;
    }
    s1[threadIdx.x] = sum; s2[threadIdx.x] = sq;
    __syncthreads();
    for (int st = 128; st > 0; st >>= 1) {
        if (threadIdx.x < st) {
            s1[threadIdx.x] += s1[threadIdx.x + st];
            s2[threadIdx.x] += s2[threadIdx.x + st];
        }
        __syncthreads();
    }
    if (threadIdx.x == 0) {
        float mean = s1[0] / (float)GSIZE;
        float var = s2[0] / (float)GSIZE - mean * mean;
        stats[bg] = make_float2(mean, rsqrtf(var + EPS));
    }
}

// ---------------- K2: QKV GEMM with fused GroupNorm on the B-operand ----------------
// qkv[b,o,w] = sum_c (scale[b,c]*x[b,c,w]+shift[b,c]) * wq[o,c] + bq[o]   (bf16 out)
__global__ __launch_bounds__(256) void qkv_gemm_kernel(
    const float* __restrict__ x, const float* __restrict__ gnw, const float* __restrict__ gnb,
    const float* __restrict__ wq, const float* __restrict__ bq,
    const float2* __restrict__ stats, bf16* __restrict__ qkv) {
    __shared__ float As[16][68];
    __shared__ float Bs[16][68];
    int b = blockIdx.z, o0 = blockIdx.y * 64, w0 = blockIdx.x * 64;
    int t = threadIdx.x, tx = t & 15, ty = t >> 4;
    int aoo = t >> 2, ac0 = (t & 3) * 4;   // A-tile load coords (64 o x 16 c)
    int bcc = t >> 4, bww = (t & 15) * 4;  // B-tile load coords (16 c x 64 w)
    float acc[4][4] = {};
    for (int c0 = 0; c0 < C; c0 += 16) {
        float4 av = *(const float4*)(wq + (size_t)(o0 + aoo) * C + c0 + ac0);
        As[ac0 + 0][aoo] = av.x; As[ac0 + 1][aoo] = av.y;
        As[ac0 + 2][aoo] = av.z; As[ac0 + 3][aoo] = av.w;

        int c = c0 + bcc;
        float2 st = stats[b * GROUPS + (c >> 4)];
        float gw = gnw[c], gb = gnb[c];
        float scale = st.y * gw;
        float shift = gb - st.x * st.y * gw;
        float4 xv = *(const float4*)(x + ((size_t)b * C + c) * W + w0 + bww);
        float4 bv = make_float4(xv.x * scale + shift, xv.y * scale + shift,
                                xv.z * scale + shift, xv.w * scale + shift);
        *(float4*)&Bs[bcc][bww] = bv;
        __syncthreads();
#pragma unroll
        for (int kk = 0; kk < 16; kk++) {
            float4 a = *(const float4*)&As[kk][ty * 4];
            float4 bb = *(const float4*)&Bs[kk][tx * 4];
            FMA16(a, bb)
        }
        __syncthreads();
    }
#pragma unroll
    for (int i = 0; i < 4; i++) {
        int o = o0 + ty * 4 + i;
        float bias = bq[o];
        unsigned lo = pack2(acc[i][0] + bias, acc[i][1] + bias);
        unsigned hi = pack2(acc[i][2] + bias, acc[i][3] + bias);
        unsigned* op = (unsigned*)(qkv + ((size_t)b * OUT3 + o) * W + w0 + tx * 4);
        op[0] = lo; op[1] = hi;
    }
}

// ---------------- K3: softmax over W for the K slice, in place (bf16 ws) ----------------
__global__ __launch_bounds__(256) void softmax_kernel(bf16* __restrict__ qkv) {
    __shared__ float sbuf[256];
    int row = blockIdx.x;  // 0..B*HIDDEN-1
    int b = row >> 9, r = row & 511;
    bf16* base = qkv + ((size_t)b * OUT3 + HIDDEN + r) * W;
    int t = threadIdx.x;
    uint4 u0 = ((const uint4*)base)[t];
    uint4 u1 = ((const uint4*)base)[256 + t];
    float v[16];
    v[0] = bf_lo(u0.x); v[1] = bf_hi(u0.x); v[2] = bf_lo(u0.y); v[3] = bf_hi(u0.y);
    v[4] = bf_lo(u0.z); v[5] = bf_hi(u0.z); v[6] = bf_lo(u0.w); v[7] = bf_hi(u0.w);
    v[8] = bf_lo(u1.x); v[9] = bf_hi(u1.x); v[10] = bf_lo(u1.y); v[11] = bf_hi(u1.y);
    v[12] = bf_lo(u1.z); v[13] = bf_hi(u1.z); v[14] = bf_lo(u1.w); v[15] = bf_hi(u1.w);
    float m = v[0];
#pragma unroll
    for (int i = 1; i < 16; i++) m = fmaxf(m, v[i]);
    sbuf[t] = m; __syncthreads();
    for (int st = 128; st > 0; st >>= 1) {
        if (t < st) sbuf[t] = fmaxf(sbuf[t], sbuf[t + st]);
        __syncthreads();
    }
    m = sbuf[0]; __syncthreads();
    float s = 0.f;
#pragma unroll
    for (int i = 0; i < 16; i++) { v[i] = __expf(v[i] - m); s += v[i]; }
    sbuf[t] = s; __syncthreads();
    for (int st = 128; st > 0; st >>= 1) {
        if (t < st) sbuf[t] += sbuf[t + st];
        __syncthreads();
    }
    float inv = 1.0f / sbuf[0];
#pragma unroll
    for (int i = 0; i < 16; i++) v[i] *= inv;
    uint4 o0, o1;
    o0.x = pack2(v[0], v[1]); o0.y = pack2(v[2], v[3]); o0.z = pack2(v[4], v[5]); o0.w = pack2(v[6], v[7]);
    o1.x = pack2(v[8], v[9]); o1.y = pack2(v[10], v[11]); o1.z = pack2(v[12], v[13]); o1.w = pack2(v[14], v[15]);
    ((uint4*)base)[t] = o0;
    ((uint4*)base)[256 + t] = o1;
}

// ---------------- K4: context[b,h,d,e] = sum_n k_sm[d,n]*v[e,n] ----------------
__global__ __launch_bounds__(256) void kv_context_kernel(const bf16* __restrict__ qkv,
                                                         float* __restrict__ ctx) {
    __shared__ float kS[64][68];
    __shared__ float vS[64][68];
    int bh = blockIdx.x;
    int b = bh >> 3, h = bh & 7;
    const bf16* kbase = qkv + ((size_t)b * OUT3 + HIDDEN + h * HD) * W;
    const bf16* vbase = qkv + ((size_t)b * OUT3 + 2 * HIDDEN + h * HD) * W;
    int t = threadIdx.x, tx = t & 15, ty = t >> 4;
    int lr = t >> 4, lc = (t & 15) * 4;
    float acc[4][4] = {};
    for (int n0 = 0; n0 < W; n0 += 64) {
#pragma unroll
        for (int rr = 0; rr < 4; rr++) {
            int row = lr + rr * 16;
            const unsigned* kp = (const unsigned*)(kbase + (size_t)row * W + n0 + lc);
            unsigned k0 = kp[0], k1 = kp[1];
            kS[lc + 0][row] = bf_lo(k0); kS[lc + 1][row] = bf_hi(k0);
            kS[lc + 2][row] = bf_lo(k1); kS[lc + 3][row] = bf_hi(k1);
            const unsigned* vp = (const unsigned*)(vbase + (size_t)row * W + n0 + lc);
            unsigned v0 = vp[0], v1 = vp[1];
            vS[lc + 0][row] = bf_lo(v0); vS[lc + 1][row] = bf_hi(v0);
            vS[lc + 2][row] = bf_lo(v1); vS[lc + 3][row] = bf_hi(v1);
        }
        __syncthreads();
#pragma unroll 8
        for (int n = 0; n < 64; n++) {
            float4 a = *(const float4*)&kS[n][ty * 4];
            float4 bb = *(const float4*)&vS[n][tx * 4];
            FMA16(a, bb)
        }
        __syncthreads();
    }
#pragma unroll
    for (int i = 0; i < 4; i++)
#pragma unroll
        for (int j = 0; j < 4; j++)
            ctx[((size_t)bh * 64 + ty * 4 + i) * 64 + tx * 4 + j] = acc[i][j];
}

// ---------------- K5: out[b,h,e,n] = sum_d ctx[d,e]*q[d,n] ----------------
__global__ __launch_bounds__(256) void apply_context_kernel(const bf16* __restrict__ qkv,
                                                            const float* __restrict__ ctx,
                                                            bf16* __restrict__ attn) {
    __shared__ float cS[64][68];
    __shared__ float qS[64][68];
    int bh = blockIdx.y;
    int b = bh >> 3, h = bh & 7;
    int n0 = blockIdx.x * 64;
    const bf16* qbase = qkv + ((size_t)b * OUT3 + h * HD) * W;
    int t = threadIdx.x, tx = t & 15, ty = t >> 4;
    int lr = t >> 4, lc = (t & 15) * 4;
#pragma unroll
    for (int rr = 0; rr < 4; rr++) {
        int row = lr + rr * 16;
        float4 cv = *(const float4*)(ctx + ((size_t)bh * 64 + row) * 64 + lc);
        *(float4*)&cS[row][lc] = cv;
        const unsigned* qp = (const unsigned*)(qbase + (size_t)row * W + n0 + lc);
        unsigned q0 = qp[0], q1 = qp[1];
        *(float4*)&qS[row][lc] = make_float4(bf_lo(q0), bf_hi(q0), bf_lo(q1), bf_hi(q1));
    }
    __syncthreads();
    float acc[4][4] = {};
#pragma unroll 8
    for (int d = 0; d < 64; d++) {
        float4 a = *(const float4*)&cS[d][ty * 4];   // e-direction
        float4 bb = *(const float4*)&qS[d][tx * 4];  // n-direction
        FMA16(a, bb)
    }
#pragma unroll
    for (int i = 0; i < 4; i++) {
        int e = ty * 4 + i;
        unsigned lo = pack2(acc[i][0], acc[i][1]);
        unsigned hi = pack2(acc[i][2], acc[i][3]);
        unsigned* op = (unsigned*)(attn + ((size_t)b * HIDDEN + h * HD + e) * W + n0 + tx * 4);
        op[0] = lo; op[1] = hi;
    }
}

// ---------------- K6: out[b,c,w] = sum_hid wo[c,hid]*attn[b,hid,w] + bo[c]  (fp32 out) ----------------
__global__ __launch_bounds__(256) void out_gemm_kernel(const bf16* __restrict__ attn,
                                                       const float* __restrict__ wo,
                                                       const float* __restrict__ bo,
                                                       float* __restrict__ out) {
    __shared__ float As[16][68];
    __shared__ float Bs[16][68];
    int b = blockIdx.z, o0 = blockIdx.y * 64, w0 = blockIdx.x * 64;
    int t = threadIdx.x, tx = t & 15, ty = t >> 4;
    int aoo = t >> 2, ac0 = (t & 3) * 4;
    int bcc = t >> 4, bww = (t & 15) * 4;
    float acc[4][4] = {};
    for (int c0 = 0; c0 < HIDDEN; c0 += 16) {
        float4 av = *(const float4*)(wo + (size_t)(o0 + aoo) * HIDDEN + c0 + ac0);
        As[ac0 + 0][aoo] = av.x; As[ac0 + 1][aoo] = av.y;
        As[ac0 + 2][aoo] = av.z; As[ac0 + 3][aoo] = av.w;

        const unsigned* bp = (const unsigned*)(attn + ((size_t)b * HIDDEN + c0 + bcc) * W + w0 + bww);
        unsigned u0 = bp[0], u1 = bp[1];
        *(float4*)&Bs[bcc][bww] = make_float4(bf_lo(u0), bf_hi(u0), bf_lo(u1), bf_hi(u1));
        __syncthreads();
#pragma unroll
        for (int kk = 0; kk < 16; kk++) {
            float4 a = *(const float4*)&As[kk][ty * 4];
            float4 bb = *(const float4*)&Bs[kk][tx * 4];
            FMA16(a, bb)
        }
        __syncthreads();
    }
#pragma unroll
    for (int i = 0; i < 4; i++) {
        int o = o0 + ty * 4 + i;
        float bias = bo[o];
        float4 ov = make_float4(acc[i][0] + bias, acc[i][1] + bias,
                                acc[i][2] + bias, acc[i][3] + bias);
        *(float4*)(out + ((size_t)b * C + o) * W + w0 + tx * 4) = ov;
    }
}

extern "C" void kernel_launch(void* const* d_in, const int* in_sizes, int n_in,
                              void* d_out, int out_size, void* d_ws, size_t ws_size,
                              hipStream_t stream) {
    const float* x   = (const float*)d_in[0];
    const float* gnw = (const float*)d_in[1];
    const float* gnb = (const float*)d_in[2];
    const float* wq  = (const float*)d_in[3];
    const float* bq  = (const float*)d_in[4];
    const float* wo  = (const float*)d_in[5];
    const float* bo  = (const float*)d_in[6];
    float* out = (float*)d_out;

    char* ws = (char*)d_ws;
    bf16* qkv     = (bf16*)ws;                          // 192 MiB: B*1536*W bf16
    bf16* attn    = (bf16*)(ws + 201326592ull);         // 64 MiB: B*512*W bf16
    float* ctx    = (float*)(ws + 268435456ull);        // 2 MiB: B*8*64*64 fp32
    float2* stats = (float2*)(ws + 270532608ull);       // 4 KiB

    gn_stats_kernel<<<B * GROUPS, 256, 0, stream>>>(x, stats);
    qkv_gemm_kernel<<<dim3(W / 64, OUT3 / 64, B), 256, 0, stream>>>(x, gnw, gnb, wq, bq, stats, qkv);
    softmax_kernel<<<B * HIDDEN, 256, 0, stream>>>(qkv);
    kv_context_kernel<<<B * HEADS, 256, 0, stream>>>(qkv, ctx);
    apply_context_kernel<<<dim3(W / 64, B * HEADS), 256, 0, stream>>>(qkv, ctx, attn);
    out_gemm_kernel<<<dim3(W / 64, C / 64, B), 256, 0, stream>>>(attn, wo, bo, out);
}

// Round 3
// 881.330 us; speedup vs baseline: 2.7541x; 2.7541x over previous
//
#include <hip/hip_runtime.h>
#include <hip/hip_bf16.h>

#define B 16
#define C 512
#define W 4096
#define HEADS 8
#define HD 64
#define GROUPS 32
#define HIDDEN 512
#define OUT3 1536
#define CPG 16
#define GSIZE (CPG * W)
#define EPS 1e-5f

using bf16 = __hip_bfloat16;
typedef __attribute__((ext_vector_type(8))) short short8;
typedef __attribute__((ext_vector_type(4))) float f32x4;

__device__ __forceinline__ float bf_lo(unsigned u) { return __uint_as_float(u << 16); }
__device__ __forceinline__ float bf_hi(unsigned u) { return __uint_as_float(u & 0xffff0000u); }
__device__ __forceinline__ unsigned short f2bf(float f) {
    unsigned u = __float_as_uint(f);
    unsigned r = 0x7fffu + ((u >> 16) & 1u);
    return (unsigned short)((u + r) >> 16);
}
__device__ __forceinline__ unsigned pack2(float a, float b) {
    return (unsigned)f2bf(a) | ((unsigned)f2bf(b) << 16);
}

// async global->LDS, 16B per lane. LDS dest = wave-uniform base + lane*16.
__device__ __forceinline__ void async16(const ushort* g, ushort* l) {
    __builtin_amdgcn_global_load_lds((const __attribute__((address_space(1))) void*)g,
                                     (__attribute__((address_space(3))) void*)l, 16, 0, 0);
}

#define FMA16(a, bb)                                                                      \
    acc[0][0] += a.x * bb.x; acc[0][1] += a.x * bb.y; acc[0][2] += a.x * bb.z; acc[0][3] += a.x * bb.w; \
    acc[1][0] += a.y * bb.x; acc[1][1] += a.y * bb.y; acc[1][2] += a.y * bb.z; acc[1][3] += a.y * bb.w; \
    acc[2][0] += a.z * bb.x; acc[2][1] += a.z * bb.y; acc[2][2] += a.z * bb.z; acc[2][3] += a.z * bb.w; \
    acc[3][0] += a.w * bb.x; acc[3][1] += a.w * bb.y; acc[3][2] += a.w * bb.z; acc[3][3] += a.w * bb.w;

// ---------------- K1: GroupNorm stats (mean, rstd) per (b, group) ----------------
__global__ __launch_bounds__(256) void gn_stats_kernel(const float* __restrict__ x,
                                                       float2* __restrict__ stats) {
    __shared__ float s1[256], s2[256];
    int bg = blockIdx.x;
    const float4* p4 = (const float4*)(x + (size_t)bg * GSIZE);
    float sum = 0.f, sq = 0.f;
    for (int i = threadIdx.x; i < GSIZE / 4; i += 256) {
        float4 u = p4[i];
        sum += u.x + u.y + u.z + u.w;
        sq += u.x * u.x + u.y * u.y + u.z * u.z + u.w * u.w;
    }
    s1[threadIdx.x] = sum; s2[threadIdx.x] = sq;
    __syncthreads();
    for (int st = 128; st > 0; st >>= 1) {
        if (threadIdx.x < st) {
            s1[threadIdx.x] += s1[threadIdx.x + st];
            s2[threadIdx.x] += s2[threadIdx.x + st];
        }
        __syncthreads();
    }
    if (threadIdx.x == 0) {
        float mean = s1[0] / (float)GSIZE;
        float var = s2[0] / (float)GSIZE - mean * mean;
        stats[bg] = make_float2(mean, rsqrtf(var + EPS));
    }
}

// ---------------- K2a: fp32 -> bf16 cast (weights) ----------------
__global__ __launch_bounds__(256) void convw_kernel(const float* __restrict__ s,
                                                    ushort* __restrict__ d, int n4) {
    int i = blockIdx.x * 256 + threadIdx.x;
    if (i >= n4) return;
    float4 v = ((const float4*)s)[i];
    ushort4 o; o.x = f2bf(v.x); o.y = f2bf(v.y); o.z = f2bf(v.z); o.w = f2bf(v.w);
    ((ushort4*)d)[i] = o;
}

// ---------------- K2b: fused GroupNorm + transpose + bf16: xnT[b][w][c] ----------------
__global__ __launch_bounds__(256) void conv_xnt_kernel(
    const float* __restrict__ x, const float* __restrict__ gnw, const float* __restrict__ gnb,
    const float2* __restrict__ stats, ushort* __restrict__ xnT) {
    __shared__ ushort tile[64][68];
    int b = blockIdx.z, c0 = blockIdx.y * 64, w0 = blockIdx.x * 64;
    int t = threadIdx.x;
    int rc = t >> 4, rw = (t & 15) * 4;
#pragma unroll
    for (int p = 0; p < 4; p++) {
        int cl = p * 16 + rc;
        int c = c0 + cl;
        float2 st = stats[b * GROUPS + (c >> 4)];
        float gw = gnw[c], gb = gnb[c];
        float scale = st.y * gw;
        float shift = gb - st.x * scale;
        float4 v = *(const float4*)(x + ((size_t)b * C + c) * W + w0 + rw);
        tile[cl][rw + 0] = f2bf(v.x * scale + shift);
        tile[cl][rw + 1] = f2bf(v.y * scale + shift);
        tile[cl][rw + 2] = f2bf(v.z * scale + shift);
        tile[cl][rw + 3] = f2bf(v.w * scale + shift);
    }
    __syncthreads();
#pragma unroll
    for (int p = 0; p < 4; p++) {
        int wl = p * 16 + rc;
        int cl = (t & 15) * 4;
        ushort4 o;
        o.x = tile[cl + 0][wl]; o.y = tile[cl + 1][wl];
        o.z = tile[cl + 2][wl]; o.w = tile[cl + 3][wl];
        *(ushort4*)(xnT + ((size_t)b * W + w0 + wl) * C + c0 + cl) = o;
    }
}

// ---------------- K3: MFMA GEMM.  D[n][m] = sum_k A[m][k]*Bw[n][k] (+bias[n]) ----------------
// A: [M x 512] bf16 row-major (per batch), Bw: [N x 512] bf16 row-major (shared).
// Tile 128(m) x 128(n), BK=32. 4 waves, 64x64 each. LDS packed [kq][row][8].
template <bool BF16_OUT>
__global__ __launch_bounds__(256) void gemm_tn_kernel(
    const ushort* __restrict__ A, const ushort* __restrict__ Bw,
    const float* __restrict__ bias, void* __restrict__ Dv,
    long aBatch, long dBatch) {
    __shared__ ushort As[4096];
    __shared__ ushort Bs[4096];
    int b = blockIdx.z;
    int m0 = blockIdx.x * 128, n0 = blockIdx.y * 128;
    const ushort* Ab = A + (size_t)b * aBatch;
    int t = threadIdx.x;
    int lane = t & 63;
    int wv = t >> 6;
    int wm = (wv & 1) * 64, wn = (wv >> 1) * 64;
    int quad = lane >> 4, lr = lane & 15;

    f32x4 acc[4][4] = {};

    int f1 = t, f2 = t + 256;
    int kq1 = f1 >> 7, r1 = f1 & 127;   // chunk f covers LDS elems [f*8, f*8+8) = [kq][row][:]
    int kq2 = f2 >> 7, r2 = f2 & 127;

    for (int k0 = 0; k0 < 512; k0 += 32) {
        async16(Ab + (size_t)(m0 + r1) * 512 + k0 + kq1 * 8, &As[f1 * 8]);
        async16(Ab + (size_t)(m0 + r2) * 512 + k0 + kq2 * 8, &As[f2 * 8]);
        async16(Bw + (size_t)(n0 + r1) * 512 + k0 + kq1 * 8, &Bs[f1 * 8]);
        async16(Bw + (size_t)(n0 + r2) * 512 + k0 + kq2 * 8, &Bs[f2 * 8]);
        __syncthreads();
        short8 af[4], bfr[4];
#pragma unroll
        for (int i = 0; i < 4; i++)
            af[i] = *(const short8*)&As[quad * 1024 + (wm + i * 16 + lr) * 8];
#pragma unroll
        for (int j = 0; j < 4; j++)
            bfr[j] = *(const short8*)&Bs[quad * 1024 + (wn + j * 16 + lr) * 8];
#pragma unroll
        for (int i = 0; i < 4; i++)
#pragma unroll
            for (int j = 0; j < 4; j++)
                acc[i][j] = __builtin_amdgcn_mfma_f32_16x16x32_bf16(af[i], bfr[j], acc[i][j], 0, 0, 0);
        __syncthreads();
    }

    // C/D layout: col(n) = lane&15, row(m) = quad*4 + reg  ->  per lane: 4 consecutive m, one n.
    if constexpr (BF16_OUT) {
        ushort* Db = (ushort*)Dv + (size_t)b * dBatch;
#pragma unroll
        for (int i = 0; i < 4; i++) {
            int mb = m0 + wm + i * 16 + quad * 4;
#pragma unroll
            for (int j = 0; j < 4; j++) {
                int n = n0 + wn + j * 16 + lr;
                float bv = bias[n];
                f32x4 v = acc[i][j];
                uint2 st;
                st.x = pack2(v.x + bv, v.y + bv);
                st.y = pack2(v.z + bv, v.w + bv);
                *(uint2*)(Db + (size_t)n * W + mb) = st;
            }
        }
    } else {
        float* Db = (float*)Dv + (size_t)b * dBatch;
#pragma unroll
        for (int i = 0; i < 4; i++) {
            int mb = m0 + wm + i * 16 + quad * 4;
#pragma unroll
            for (int j = 0; j < 4; j++) {
                int n = n0 + wn + j * 16 + lr;
                float bv = bias[n];
                f32x4 v = acc[i][j];
                float4 st = make_float4(v.x + bv, v.y + bv, v.z + bv, v.w + bv);
                *(float4*)(Db + (size_t)n * W + mb) = st;
            }
        }
    }
}

// ---------------- K4: softmax over W for the K slice, in place (bf16 ws) ----------------
__global__ __launch_bounds__(256) void softmax_kernel(bf16* __restrict__ qkv) {
    __shared__ float sbuf[256];
    int row = blockIdx.x;
    int b = row >> 9, r = row & 511;
    bf16* base = qkv + ((size_t)b * OUT3 + HIDDEN + r) * W;
    int t = threadIdx.x;
    uint4 u0 = ((const uint4*)base)[t];
    uint4 u1 = ((const uint4*)base)[256 + t];
    float v[16];
    v[0] = bf_lo(u0.x); v[1] = bf_hi(u0.x); v[2] = bf_lo(u0.y); v[3] = bf_hi(u0.y);
    v[4] = bf_lo(u0.z); v[5] = bf_hi(u0.z); v[6] = bf_lo(u0.w); v[7] = bf_hi(u0.w);
    v[8] = bf_lo(u1.x); v[9] = bf_hi(u1.x); v[10] = bf_lo(u1.y); v[11] = bf_hi(u1.y);
    v[12] = bf_lo(u1.z); v[13] = bf_hi(u1.z); v[14] = bf_lo(u1.w); v[15] = bf_hi(u1.w);
    float m = v[0];
#pragma unroll
    for (int i = 1; i < 16; i++) m = fmaxf(m, v[i]);
    sbuf[t] = m; __syncthreads();
    for (int st = 128; st > 0; st >>= 1) {
        if (t < st) sbuf[t] = fmaxf(sbuf[t], sbuf[t + st]);
        __syncthreads();
    }
    m = sbuf[0]; __syncthreads();
    float s = 0.f;
#pragma unroll
    for (int i = 0; i < 16; i++) { v[i] = __expf(v[i] - m); s += v[i]; }
    sbuf[t] = s; __syncthreads();
    for (int st = 128; st > 0; st >>= 1) {
        if (t < st) sbuf[t] += sbuf[t + st];
        __syncthreads();
    }
    float inv = 1.0f / sbuf[0];
#pragma unroll
    for (int i = 0; i < 16; i++) v[i] *= inv;
    uint4 o0, o1;
    o0.x = pack2(v[0], v[1]); o0.y = pack2(v[2], v[3]); o0.z = pack2(v[4], v[5]); o0.w = pack2(v[6], v[7]);
    o1.x = pack2(v[8], v[9]); o1.y = pack2(v[10], v[11]); o1.z = pack2(v[12], v[13]); o1.w = pack2(v[14], v[15]);
    ((uint4*)base)[t] = o0;
    ((uint4*)base)[256 + t] = o1;
}

// ---------------- K5: context[b,h,d,e] = sum_n k_sm[d,n]*v[e,n] ----------------
__global__ __launch_bounds__(256) void kv_context_kernel(const bf16* __restrict__ qkv,
                                                         float* __restrict__ ctx) {
    __shared__ float kS[64][68];
    __shared__ float vS[64][68];
    int bh = blockIdx.x;
    int b = bh >> 3, h = bh & 7;
    const bf16* kbase = qkv + ((size_t)b * OUT3 + HIDDEN + h * HD) * W;
    const bf16* vbase = qkv + ((size_t)b * OUT3 + 2 * HIDDEN + h * HD) * W;
    int t = threadIdx.x, tx = t & 15, ty = t >> 4;
    int lr = t >> 4, lc = (t & 15) * 4;
    float acc[4][4] = {};
    for (int n0 = 0; n0 < W; n0 += 64) {
#pragma unroll
        for (int rr = 0; rr < 4; rr++) {
            int row = lr + rr * 16;
            const unsigned* kp = (const unsigned*)(kbase + (size_t)row * W + n0 + lc);
            unsigned k0 = kp[0], k1 = kp[1];
            kS[lc + 0][row] = bf_lo(k0); kS[lc + 1][row] = bf_hi(k0);
            kS[lc + 2][row] = bf_lo(k1); kS[lc + 3][row] = bf_hi(k1);
            const unsigned* vp = (const unsigned*)(vbase + (size_t)row * W + n0 + lc);
            unsigned v0 = vp[0], v1 = vp[1];
            vS[lc + 0][row] = bf_lo(v0); vS[lc + 1][row] = bf_hi(v0);
            vS[lc + 2][row] = bf_lo(v1); vS[lc + 3][row] = bf_hi(v1);
        }
        __syncthreads();
#pragma unroll 8
        for (int n = 0; n < 64; n++) {
            float4 a = *(const float4*)&kS[n][ty * 4];
            float4 bb = *(const float4*)&vS[n][tx * 4];
            FMA16(a, bb)
        }
        __syncthreads();
    }
#pragma unroll
    for (int i = 0; i < 4; i++)
#pragma unroll
        for (int j = 0; j < 4; j++)
            ctx[((size_t)bh * 64 + ty * 4 + i) * 64 + tx * 4 + j] = acc[i][j];
}

// ---------------- K6: attnT[b, w, h*64+e] = sum_d ctx[d,e]*q[d,n=w] ----------------
__global__ __launch_bounds__(256) void apply_context_kernel(const bf16* __restrict__ qkv,
                                                            const float* __restrict__ ctx,
                                                            ushort* __restrict__ attnT) {
    __shared__ float cS[64][68];
    __shared__ float qS[64][68];
    int bh = blockIdx.y;
    int b = bh >> 3, h = bh & 7;
    int n0 = blockIdx.x * 64;
    const bf16* qbase = qkv + ((size_t)b * OUT3 + h * HD) * W;
    int t = threadIdx.x, tx = t & 15, ty = t >> 4;
    int lr = t >> 4, lc = (t & 15) * 4;
#pragma unroll
    for (int rr = 0; rr < 4; rr++) {
        int row = lr + rr * 16;
        float4 cv = *(const float4*)(ctx + ((size_t)bh * 64 + row) * 64 + lc);
        *(float4*)&cS[row][lc] = cv;
        const unsigned* qp = (const unsigned*)(qbase + (size_t)row * W + n0 + lc);
        unsigned q0 = qp[0], q1 = qp[1];
        *(float4*)&qS[row][lc] = make_float4(bf_lo(q0), bf_hi(q0), bf_lo(q1), bf_hi(q1));
    }
    __syncthreads();
    float acc[4][4] = {};   // acc[i][j] = out[n = ty*4+i][e = tx*4+j]
#pragma unroll 8
    for (int d = 0; d < 64; d++) {
        float4 a = *(const float4*)&qS[d][ty * 4];   // n-direction
        float4 bb = *(const float4*)&cS[d][tx * 4];  // e-direction
        FMA16(a, bb)
    }
#pragma unroll
    for (int i = 0; i < 4; i++) {
        int w = n0 + ty * 4 + i;
        uint2 st;
        st.x = pack2(acc[i][0], acc[i][1]);
        st.y = pack2(acc[i][2], acc[i][3]);
        *(uint2*)(attnT + ((size_t)b * W + w) * HIDDEN + h * HD + tx * 4) = st;
    }
}

extern "C" void kernel_launch(void* const* d_in, const int* in_sizes, int n_in,
                              void* d_out, int out_size, void* d_ws, size_t ws_size,
                              hipStream_t stream) {
    const float* x   = (const float*)d_in[0];
    const float* gnw = (const float*)d_in[1];
    const float* gnb = (const float*)d_in[2];
    const float* wq  = (const float*)d_in[3];
    const float* bq  = (const float*)d_in[4];
    const float* wo  = (const float*)d_in[5];
    const float* bo  = (const float*)d_in[6];
    float* out = (float*)d_out;

    char* ws = (char*)d_ws;
    // Lifetime-aliased layout (total = 258 MiB, same footprint as round 2):
    ushort* qkv   = (ushort*)ws;                    // [0, 192Mi) qkv[b][o][w] bf16
    ushort* xnT   = (ushort*)(ws + 201326592ull);   // [192Mi, 256Mi) xnT, later attnT
    ushort* attnT = xnT;
    char*   r256  = ws + 268435456ull;              // [256Mi, 258Mi)
    ushort* wqb   = (ushort*)r256;                  //   wqb (live until qkv gemm)
    float*  ctx   = (float*)r256;                   //   ctx (live K5->K6, after wqb dead)
    float2* stats = (float2*)(ws + 270532608ull);   // 4 KiB
    ushort* wob   = qkv;                            // reconverted after q consumed (qkv dead)

    gn_stats_kernel<<<B * GROUPS, 256, 0, stream>>>(x, stats);
    convw_kernel<<<(OUT3 * C / 4 + 255) / 256, 256, 0, stream>>>(wq, wqb, OUT3 * C / 4);
    conv_xnt_kernel<<<dim3(W / 64, C / 64, B), 256, 0, stream>>>(x, gnw, gnb, stats, xnT);
    gemm_tn_kernel<true><<<dim3(W / 128, OUT3 / 128, B), 256, 0, stream>>>(
        xnT, wqb, bq, qkv, (long)W * C, (long)OUT3 * W);
    softmax_kernel<<<B * HIDDEN, 256, 0, stream>>>((bf16*)qkv);
    kv_context_kernel<<<B * HEADS, 256, 0, stream>>>((const bf16*)qkv, ctx);
    apply_context_kernel<<<dim3(W / 64, B * HEADS), 256, 0, stream>>>((const bf16*)qkv, ctx, attnT);
    convw_kernel<<<(C * HIDDEN / 4 + 255) / 256, 256, 0, stream>>>(wo, wob, C * HIDDEN / 4);
    gemm_tn_kernel<false><<<dim3(W / 128, C / 128, B), 256, 0, stream>>>(
        attnT, wob, bo, out, (long)W * HIDDEN, (long)C * W);
}

// Round 4
// 750.431 us; speedup vs baseline: 3.2346x; 1.1744x over previous
//
#include <hip/hip_runtime.h>
#include <hip/hip_bf16.h>

#define B 16
#define C 512
#define W 4096
#define HEADS 8
#define HD 64
#define GROUPS 32
#define HIDDEN 512
#define OUT3 1536
#define CPG 16
#define GSIZE (CPG * W)
#define EPS 1e-5f

using bf16 = __hip_bfloat16;
typedef __attribute__((ext_vector_type(8))) short short8;
typedef __attribute__((ext_vector_type(4))) float f32x4;

__device__ __forceinline__ float bf_lo(unsigned u) { return __uint_as_float(u << 16); }
__device__ __forceinline__ float bf_hi(unsigned u) { return __uint_as_float(u & 0xffff0000u); }
__device__ __forceinline__ unsigned short f2bf(float f) {
    unsigned u = __float_as_uint(f);
    unsigned r = 0x7fffu + ((u >> 16) & 1u);
    return (unsigned short)((u + r) >> 16);
}
__device__ __forceinline__ unsigned pack2(float a, float b) {
    return (unsigned)f2bf(a) | ((unsigned)f2bf(b) << 16);
}

// async global->LDS, 16B per lane. LDS dest = wave-uniform base + lane*16.
__device__ __forceinline__ void async16(const ushort* g, ushort* l) {
    __builtin_amdgcn_global_load_lds((const __attribute__((address_space(1))) void*)g,
                                     (__attribute__((address_space(3))) void*)l, 16, 0, 0);
}

#define FMA16(a, bb)                                                                      \
    acc[0][0] += a.x * bb.x; acc[0][1] += a.x * bb.y; acc[0][2] += a.x * bb.z; acc[0][3] += a.x * bb.w; \
    acc[1][0] += a.y * bb.x; acc[1][1] += a.y * bb.y; acc[1][2] += a.y * bb.z; acc[1][3] += a.y * bb.w; \
    acc[2][0] += a.z * bb.x; acc[2][1] += a.z * bb.y; acc[2][2] += a.z * bb.z; acc[2][3] += a.z * bb.w; \
    acc[3][0] += a.w * bb.x; acc[3][1] += a.w * bb.y; acc[3][2] += a.w * bb.z; acc[3][3] += a.w * bb.w;

// ---------------- K1: GroupNorm stats (mean, rstd) per (b, group) ----------------
__global__ __launch_bounds__(256) void gn_stats_kernel(const float* __restrict__ x,
                                                       float2* __restrict__ stats) {
    __shared__ float s1[256], s2[256];
    int bg = blockIdx.x;
    const float4* p4 = (const float4*)(x + (size_t)bg * GSIZE);
    float sum = 0.f, sq = 0.f;
    for (int i = threadIdx.x; i < GSIZE / 4; i += 256) {
        float4 u = p4[i];
        sum += u.x + u.y + u.z + u.w;
        sq += u.x * u.x + u.y * u.y + u.z * u.z + u.w * u.w;
    }
    s1[threadIdx.x] = sum; s2[threadIdx.x] = sq;
    __syncthreads();
    for (int st = 128; st > 0; st >>= 1) {
        if (threadIdx.x < st) {
            s1[threadIdx.x] += s1[threadIdx.x + st];
            s2[threadIdx.x] += s2[threadIdx.x + st];
        }
        __syncthreads();
    }
    if (threadIdx.x == 0) {
        float mean = s1[0] / (float)GSIZE;
        float var = s2[0] / (float)GSIZE - mean * mean;
        stats[bg] = make_float2(mean, rsqrtf(var + EPS));
    }
}

// ---------------- K2a: fp32 -> bf16 cast (weights) ----------------
__global__ __launch_bounds__(256) void convw_kernel(const float* __restrict__ s,
                                                    ushort* __restrict__ d, int n4) {
    int i = blockIdx.x * 256 + threadIdx.x;
    if (i >= n4) return;
    float4 v = ((const float4*)s)[i];
    ushort4 o; o.x = f2bf(v.x); o.y = f2bf(v.y); o.z = f2bf(v.z); o.w = f2bf(v.w);
    ((ushort4*)d)[i] = o;
}

// ---------------- K2b: fused GroupNorm + transpose + bf16: xnT[b][w][c] ----------------
__global__ __launch_bounds__(256) void conv_xnt_kernel(
    const float* __restrict__ x, const float* __restrict__ gnw, const float* __restrict__ gnb,
    const float2* __restrict__ stats, ushort* __restrict__ xnT) {
    __shared__ ushort tile[64][68];
    int b = blockIdx.z, c0 = blockIdx.y * 64, w0 = blockIdx.x * 64;
    int t = threadIdx.x;
    int rc = t >> 4, rw = (t & 15) * 4;
#pragma unroll
    for (int p = 0; p < 4; p++) {
        int cl = p * 16 + rc;
        int c = c0 + cl;
        float2 st = stats[b * GROUPS + (c >> 4)];
        float gw = gnw[c], gb = gnb[c];
        float scale = st.y * gw;
        float shift = gb - st.x * scale;
        float4 v = *(const float4*)(x + ((size_t)b * C + c) * W + w0 + rw);
        tile[cl][rw + 0] = f2bf(v.x * scale + shift);
        tile[cl][rw + 1] = f2bf(v.y * scale + shift);
        tile[cl][rw + 2] = f2bf(v.z * scale + shift);
        tile[cl][rw + 3] = f2bf(v.w * scale + shift);
    }
    __syncthreads();
#pragma unroll
    for (int p = 0; p < 4; p++) {
        int wl = p * 16 + rc;
        int cl = (t & 15) * 4;
        ushort4 o;
        o.x = tile[cl + 0][wl]; o.y = tile[cl + 1][wl];
        o.z = tile[cl + 2][wl]; o.w = tile[cl + 3][wl];
        *(ushort4*)(xnT + ((size_t)b * W + w0 + wl) * C + c0 + cl) = o;
    }
}

// ---------------- K3: MFMA GEMM, BK=64.  D[n][m] = sum_k A[m][k]*Bw[n][k] (+bias[n]) ----------------
// A: [M x 512] bf16 row-major (per batch), Bw: [N x 512] bf16 row-major (shared).
// Tile 128(m) x 128(n). 4 waves, 64x64 each. LDS packed [kq 0..7][row 0..127][8].
template <bool BF16_OUT>
__global__ __launch_bounds__(256) void gemm_tn_kernel(
    const ushort* __restrict__ A, const ushort* __restrict__ Bw,
    const float* __restrict__ bias, void* __restrict__ Dv,
    long aBatch, long dBatch) {
    __shared__ ushort As[8192];   // 16 KB
    __shared__ ushort Bs[8192];   // 16 KB
    int b = blockIdx.z;
    int m0 = blockIdx.x * 128, n0 = blockIdx.y * 128;
    const ushort* Ab = A + (size_t)b * aBatch;
    int t = threadIdx.x;
    int lane = t & 63;
    int wv = t >> 6;
    int wm = (wv & 1) * 64, wn = (wv >> 1) * 64;
    int quad = lane >> 4, lr = lane & 15;

    f32x4 acc[4][4] = {};

    for (int k0 = 0; k0 < 512; k0 += 64) {
#pragma unroll
        for (int i = 0; i < 4; i++) {
            int f = t + 256 * i;
            int kq = f >> 7, r = f & 127;
            async16(Ab + (size_t)(m0 + r) * 512 + k0 + kq * 8, &As[f * 8]);
            async16(Bw + (size_t)(n0 + r) * 512 + k0 + kq * 8, &Bs[f * 8]);
        }
        __syncthreads();
#pragma unroll
        for (int ks = 0; ks < 2; ks++) {
            int kb = (ks * 4 + quad) * 1024;
            short8 af[4], bfr[4];
#pragma unroll
            for (int i = 0; i < 4; i++)
                af[i] = *(const short8*)&As[kb + (wm + i * 16 + lr) * 8];
#pragma unroll
            for (int j = 0; j < 4; j++)
                bfr[j] = *(const short8*)&Bs[kb + (wn + j * 16 + lr) * 8];
#pragma unroll
            for (int i = 0; i < 4; i++)
#pragma unroll
                for (int j = 0; j < 4; j++)
                    acc[i][j] = __builtin_amdgcn_mfma_f32_16x16x32_bf16(af[i], bfr[j], acc[i][j], 0, 0, 0);
        }
        __syncthreads();
    }

    // C/D layout: col(n) = lane&15, row(m) = quad*4 + reg.
    if constexpr (BF16_OUT) {
        ushort* Db = (ushort*)Dv + (size_t)b * dBatch;
#pragma unroll
        for (int i = 0; i < 4; i++) {
            int mb = m0 + wm + i * 16 + quad * 4;
#pragma unroll
            for (int j = 0; j < 4; j++) {
                int n = n0 + wn + j * 16 + lr;
                float bv = bias[n];
                f32x4 v = acc[i][j];
                uint2 st;
                st.x = pack2(v.x + bv, v.y + bv);
                st.y = pack2(v.z + bv, v.w + bv);
                *(uint2*)(Db + (size_t)n * W + mb) = st;
            }
        }
    } else {
        float* Db = (float*)Dv + (size_t)b * dBatch;
#pragma unroll
        for (int i = 0; i < 4; i++) {
            int mb = m0 + wm + i * 16 + quad * 4;
#pragma unroll
            for (int j = 0; j < 4; j++) {
                int n = n0 + wn + j * 16 + lr;
                float bv = bias[n];
                f32x4 v = acc[i][j];
                float4 st = make_float4(v.x + bv, v.y + bv, v.z + bv, v.w + bv);
                *(float4*)(Db + (size_t)n * W + mb) = st;
            }
        }
    }
}

// ---------------- K4: per-row softmax stats of K: (max, 1/sum(exp)). Also zeroes ctx. ----------------
__global__ __launch_bounds__(256) void kstats_kernel(const ushort* __restrict__ qkv,
                                                     float2* __restrict__ kst,
                                                     float* __restrict__ ctx) {
    __shared__ float sbuf[256];
    int row = blockIdx.x;  // 0..B*HIDDEN-1
    int t = threadIdx.x;
    if (t < 64) ctx[(size_t)row * 64 + t] = 0.f;  // 8192*64 = full 2 MiB ctx
    int b = row >> 9, r = row & 511;
    const uint4* base = (const uint4*)(qkv + ((size_t)b * OUT3 + HIDDEN + r) * W);
    uint4 u0 = base[t];
    uint4 u1 = base[256 + t];
    float v[16];
    v[0] = bf_lo(u0.x); v[1] = bf_hi(u0.x); v[2] = bf_lo(u0.y); v[3] = bf_hi(u0.y);
    v[4] = bf_lo(u0.z); v[5] = bf_hi(u0.z); v[6] = bf_lo(u0.w); v[7] = bf_hi(u0.w);
    v[8] = bf_lo(u1.x); v[9] = bf_hi(u1.x); v[10] = bf_lo(u1.y); v[11] = bf_hi(u1.y);
    v[12] = bf_lo(u1.z); v[13] = bf_hi(u1.z); v[14] = bf_lo(u1.w); v[15] = bf_hi(u1.w);
    float m = v[0];
#pragma unroll
    for (int i = 1; i < 16; i++) m = fmaxf(m, v[i]);
    sbuf[t] = m; __syncthreads();
    for (int st = 128; st > 0; st >>= 1) {
        if (t < st) sbuf[t] = fmaxf(sbuf[t], sbuf[t + st]);
        __syncthreads();
    }
    m = sbuf[0]; __syncthreads();
    float s = 0.f;
#pragma unroll
    for (int i = 0; i < 16; i++) s += __expf(v[i] - m);
    sbuf[t] = s; __syncthreads();
    for (int st = 128; st > 0; st >>= 1) {
        if (t < st) sbuf[t] += sbuf[t + st];
        __syncthreads();
    }
    if (t == 0) kst[row] = make_float2(m, 1.0f / sbuf[0]);
}

// ---------------- K5: ctx[b,h,d,e] += sum_{n in slice} exp(k[d,n]-m_d)*v[e,n] ----------------
__global__ __launch_bounds__(256) void kv_context_kernel(const ushort* __restrict__ qkv,
                                                         const float2* __restrict__ kst,
                                                         float* __restrict__ ctx) {
    __shared__ float kS[64][68];
    __shared__ float vS[64][68];
    int bh = blockIdx.y;
    int b = bh >> 3, h = bh & 7;
    int nbase = blockIdx.x * 512;
    const ushort* kbase = qkv + ((size_t)b * OUT3 + HIDDEN + h * HD) * W;
    const ushort* vbase = qkv + ((size_t)b * OUT3 + 2 * HIDDEN + h * HD) * W;
    int t = threadIdx.x, tx = t & 15, ty = t >> 4;
    int lr = t >> 4, lc = (t & 15) * 4;
    float acc[4][4] = {};
    for (int n0 = nbase; n0 < nbase + 512; n0 += 64) {
#pragma unroll
        for (int rr = 0; rr < 4; rr++) {
            int row = lr + rr * 16;
            float m = kst[b * HIDDEN + h * HD + row].x;
            const unsigned* kp = (const unsigned*)(kbase + (size_t)row * W + n0 + lc);
            unsigned k0 = kp[0], k1 = kp[1];
            kS[lc + 0][row] = __expf(bf_lo(k0) - m);
            kS[lc + 1][row] = __expf(bf_hi(k0) - m);
            kS[lc + 2][row] = __expf(bf_lo(k1) - m);
            kS[lc + 3][row] = __expf(bf_hi(k1) - m);
            const unsigned* vp = (const unsigned*)(vbase + (size_t)row * W + n0 + lc);
            unsigned v0 = vp[0], v1 = vp[1];
            vS[lc + 0][row] = bf_lo(v0); vS[lc + 1][row] = bf_hi(v0);
            vS[lc + 2][row] = bf_lo(v1); vS[lc + 3][row] = bf_hi(v1);
        }
        __syncthreads();
#pragma unroll 8
        for (int n = 0; n < 64; n++) {
            float4 a = *(const float4*)&kS[n][ty * 4];
            float4 bb = *(const float4*)&vS[n][tx * 4];
            FMA16(a, bb)
        }
        __syncthreads();
    }
#pragma unroll
    for (int i = 0; i < 4; i++)
#pragma unroll
        for (int j = 0; j < 4; j++)
            atomicAdd(&ctx[((size_t)bh * 64 + ty * 4 + i) * 64 + tx * 4 + j], acc[i][j]);
}

// ---------------- K6: attnT[b, w, h*64+e] = sum_d (ctx[d,e]*inv_s[d]) * q[d,n=w] ----------------
__global__ __launch_bounds__(256) void apply_context_kernel(const ushort* __restrict__ qkv,
                                                            const float* __restrict__ ctx,
                                                            const float2* __restrict__ kst,
                                                            ushort* __restrict__ attnT) {
    __shared__ float cS[64][68];
    __shared__ float qS[64][68];
    int bh = blockIdx.y;
    int b = bh >> 3, h = bh & 7;
    int n0 = blockIdx.x * 64;
    const ushort* qbase = qkv + ((size_t)b * OUT3 + h * HD) * W;
    int t = threadIdx.x, tx = t & 15, ty = t >> 4;
    int lr = t >> 4, lc = (t & 15) * 4;
#pragma unroll
    for (int rr = 0; rr < 4; rr++) {
        int row = lr + rr * 16;
        float inv = kst[b * HIDDEN + h * HD + row].y;
        float4 cv = *(const float4*)(ctx + ((size_t)bh * 64 + row) * 64 + lc);
        cv.x *= inv; cv.y *= inv; cv.z *= inv; cv.w *= inv;
        *(float4*)&cS[row][lc] = cv;
        const unsigned* qp = (const unsigned*)(qbase + (size_t)row * W + n0 + lc);
        unsigned q0 = qp[0], q1 = qp[1];
        *(float4*)&qS[row][lc] = make_float4(bf_lo(q0), bf_hi(q0), bf_lo(q1), bf_hi(q1));
    }
    __syncthreads();
    float acc[4][4] = {};   // acc[i][j] = out[n = ty*4+i][e = tx*4+j]
#pragma unroll 8
    for (int d = 0; d < 64; d++) {
        float4 a = *(const float4*)&qS[d][ty * 4];   // n-direction
        float4 bb = *(const float4*)&cS[d][tx * 4];  // e-direction
        FMA16(a, bb)
    }
#pragma unroll
    for (int i = 0; i < 4; i++) {
        int w = n0 + ty * 4 + i;
        uint2 st;
        st.x = pack2(acc[i][0], acc[i][1]);
        st.y = pack2(acc[i][2], acc[i][3]);
        *(uint2*)(attnT + ((size_t)b * W + w) * HIDDEN + h * HD + tx * 4) = st;
    }
}

extern "C" void kernel_launch(void* const* d_in, const int* in_sizes, int n_in,
                              void* d_out, int out_size, void* d_ws, size_t ws_size,
                              hipStream_t stream) {
    const float* x   = (const float*)d_in[0];
    const float* gnw = (const float*)d_in[1];
    const float* gnb = (const float*)d_in[2];
    const float* wq  = (const float*)d_in[3];
    const float* bq  = (const float*)d_in[4];
    const float* wo  = (const float*)d_in[5];
    const float* bo  = (const float*)d_in[6];
    float* out = (float*)d_out;

    char* ws = (char*)d_ws;
    // Lifetime-aliased layout (258 MiB, proven footprint):
    ushort* qkv   = (ushort*)ws;                    // [0, 192Mi) qkv[b][o][w] bf16
    ushort* xnT   = (ushort*)(ws + 201326592ull);   // [192Mi, 256Mi) xnT, later attnT
    ushort* attnT = xnT;
    char*   r256  = ws + 268435456ull;              // [256Mi, 258Mi)
    ushort* wqb   = (ushort*)r256;                  //   wqb (dead after qkv gemm)
    float*  ctx   = (float*)r256;                   //   ctx (live kstats..apply, 2 MiB)
    float2* stats = (float2*)(ws + 270532608ull);   // 4 KiB
    ushort* wob   = qkv;                            // reuses qkv after q consumed
    float2* kst   = (float2*)d_out;                 // 64 KiB scratch in d_out; overwritten by final gemm

    gn_stats_kernel<<<B * GROUPS, 256, 0, stream>>>(x, stats);
    convw_kernel<<<(OUT3 * C / 4 + 255) / 256, 256, 0, stream>>>(wq, wqb, OUT3 * C / 4);
    conv_xnt_kernel<<<dim3(W / 64, C / 64, B), 256, 0, stream>>>(x, gnw, gnb, stats, xnT);
    gemm_tn_kernel<true><<<dim3(W / 128, OUT3 / 128, B), 256, 0, stream>>>(
        xnT, wqb, bq, qkv, (long)W * C, (long)OUT3 * W);
    kstats_kernel<<<B * HIDDEN, 256, 0, stream>>>(qkv, kst, ctx);
    kv_context_kernel<<<dim3(8, B * HEADS), 256, 0, stream>>>(qkv, kst, ctx);
    apply_context_kernel<<<dim3(W / 64, B * HEADS), 256, 0, stream>>>(qkv, ctx, kst, attnT);
    convw_kernel<<<(C * HIDDEN / 4 + 255) / 256, 256, 0, stream>>>(wo, wob, C * HIDDEN / 4);
    gemm_tn_kernel<false><<<dim3(W / 128, C / 128, B), 256, 0, stream>>>(
        attnT, wob, bo, out, (long)W * HIDDEN, (long)C * W);
}